// Round 2
// baseline (2027.115 us; speedup 1.0000x reference)
//
#include <hip/hip_runtime.h>
#include <hip/hip_bf16.h>
#include <math.h>

#define FTS 256
#define IN_DIM 255
#define U0 512
#define U1 256
#define DIM 64
#define EMB 512
#define BATCH 256

// C[f,m,n] = act( sum_k A[f,m,k] * W[f,k,n] + bias[f,n] )
// ACT: 0 = relu, 1 = sigmoid
// A_XLAYOUT: A is x with layout [batch, fts, IN_DIM] (implicit transpose)
// OUT_TRANS: store C as out[m, f, n] (final output transpose), N must be FTS
template<int ACT, bool A_XLAYOUT, bool OUT_TRANS>
__global__ __launch_bounds__(256)
void fat_gemm(const float* __restrict__ A, const float* __restrict__ W,
              const float* __restrict__ bias, float* __restrict__ C,
              int M, int K, int N) {
    const int f   = blockIdx.z;
    const int bm  = blockIdx.y * 64;
    const int bn  = blockIdx.x * 64;
    const int tid = threadIdx.x;

    __shared__ float As[16][68];
    __shared__ float Bs[16][68];

    const int tx = tid & 15;   // n-group: cols tx*4 .. tx*4+3
    const int ty = tid >> 4;   // m-group: rows ty*4 .. ty*4+3

    float acc[4][4];
#pragma unroll
    for (int i = 0; i < 4; i++)
#pragma unroll
        for (int j = 0; j < 4; j++) acc[i][j] = 0.f;

    const float* Wf = W + (size_t)f * K * N;

    for (int k0 = 0; k0 < K; k0 += 16) {
        // A tile: 64 rows (m) x 16 (k)
#pragma unroll
        for (int i = 0; i < 4; i++) {
            int e = i * 256 + tid;
            int r = e >> 4, c = e & 15;
            int k = k0 + c;
            float v = 0.f;
            if (k < K) {
                size_t idx;
                if (A_XLAYOUT) idx = (size_t)(bm + r) * (FTS * IN_DIM) + (size_t)f * IN_DIM + k;
                else           idx = (size_t)f * M * K + (size_t)(bm + r) * K + k;
                v = A[idx];
            }
            As[c][r] = v;
        }
        // B tile: 16 (k) x 64 (n)
#pragma unroll
        for (int i = 0; i < 4; i++) {
            int e = i * 256 + tid;
            int c = e >> 6, j = e & 63;
            int k = k0 + c;
            float v = 0.f;
            if (k < K) v = Wf[(size_t)k * N + bn + j];
            Bs[c][j] = v;
        }
        __syncthreads();
#pragma unroll
        for (int kk = 0; kk < 16; kk++) {
            float4 a = *(const float4*)&As[kk][ty * 4];
            float4 b = *(const float4*)&Bs[kk][tx * 4];
            float av[4] = {a.x, a.y, a.z, a.w};
            float bv[4] = {b.x, b.y, b.z, b.w};
#pragma unroll
            for (int i = 0; i < 4; i++)
#pragma unroll
                for (int j = 0; j < 4; j++)
                    acc[i][j] = fmaf(av[i], bv[j], acc[i][j]);
        }
        __syncthreads();
    }

#pragma unroll
    for (int j = 0; j < 4; j++) {
        float bval = bias[(size_t)f * N + bn + tx * 4 + j];
#pragma unroll
        for (int i = 0; i < 4; i++) {
            float v = acc[i][j] + bval;
            if (ACT == 0) v = v > 0.f ? v : 0.f;
            else          v = 1.f / (1.f + expf(-v));
            int row = bm + ty * 4 + i;
            int col = bn + tx * 4 + j;
            size_t oidx;
            if (OUT_TRANS) oidx = (size_t)row * ((size_t)FTS * N) + (size_t)f * N + col;
            else           oidx = (size_t)f * M * N + (size_t)row * N + col;
            C[oidx] = v;
        }
    }
}

// Vector quantization with DOUBLE-precision distances to eliminate argmin
// flips vs the fp64-ish numpy reference. dist = ||h||^2 - 2 h.c + ||c||^2,
// all accumulated in f64. First-min tie-break (ascending code index).
__global__ __launch_bounds__(256)
void vq_kernel(const float* __restrict__ h, const float* __restrict__ cbk,
               float* __restrict__ q) {
    __shared__ float  cb[64][65];   // 64 codes x 64 dims, padded
    __shared__ double cbn[64];      // per-code squared norms (f64)

    const int row = blockIdx.x * 256 + threadIdx.x;

    float hv[64];
#pragma unroll
    for (int i = 0; i < 16; i++) {
        float4 t = *(const float4*)&h[(size_t)row * 64 + i * 4];
        hv[i * 4 + 0] = t.x; hv[i * 4 + 1] = t.y;
        hv[i * 4 + 2] = t.z; hv[i * 4 + 3] = t.w;
    }
    double hh = 0.0;
#pragma unroll
    for (int d = 0; d < 64; d++) hh = fma((double)hv[d], (double)hv[d], hh);

    double best = 1e300;
    int    bidx = 0;

    for (int ct = 0; ct < EMB / 64; ct++) {
        __syncthreads();
#pragma unroll
        for (int i = 0; i < 16; i++) {
            int e = i * 256 + threadIdx.x;
            int c = e >> 6, d = e & 63;
            cb[c][d] = cbk[(size_t)(ct * 64 + c) * 64 + d];
        }
        __syncthreads();
        if (threadIdx.x < 64) {
            double s = 0.0;
#pragma unroll
            for (int d = 0; d < 64; d++) {
                double v = (double)cb[threadIdx.x][d];
                s = fma(v, v, s);
            }
            cbn[threadIdx.x] = s;
        }
        __syncthreads();
        for (int c = 0; c < 64; c++) {
            double dot = 0.0;
#pragma unroll
            for (int d = 0; d < 64; d++)
                dot = fma((double)hv[d], (double)cb[c][d], dot);
            double dist = hh - 2.0 * dot + cbn[c];
            if (dist < best) { best = dist; bidx = ct * 64 + c; }
        }
    }

#pragma unroll
    for (int i = 0; i < 16; i++) {
        float4 t = *(const float4*)&cbk[(size_t)bidx * 64 + i * 4];
        *(float4*)&q[(size_t)row * 64 + i * 4] = t;
    }
}

extern "C" void kernel_launch(void* const* d_in, const int* in_sizes, int n_in,
                              void* d_out, int out_size, void* d_ws, size_t ws_size,
                              hipStream_t stream) {
    const float* x   = (const float*)d_in[0];
    const float* w1  = (const float*)d_in[1];
    const float* b1  = (const float*)d_in[2];
    const float* w2  = (const float*)d_in[3];
    const float* b2  = (const float*)d_in[4];
    const float* w3  = (const float*)d_in[5];
    const float* b3  = (const float*)d_in[6];
    const float* cbk = (const float*)d_in[7];
    const float* w4  = (const float*)d_in[8];
    const float* b4  = (const float*)d_in[9];
    const float* w5  = (const float*)d_in[10];
    const float* b5  = (const float*)d_in[11];
    const float* w6  = (const float*)d_in[12];
    const float* b6  = (const float*)d_in[13];
    float* out = (float*)d_out;

    float* ws = (float*)d_ws;
    float* h1 = ws;                                   // [256,256,512]
    float* h2 = h1 + (size_t)FTS * BATCH * U0;        // [256,256,256]
    float* h3 = h2 + (size_t)FTS * BATCH * U1;        // [256,256, 64]
    float* q  = h3 + (size_t)FTS * BATCH * DIM;       // [256,256, 64]
    float* y1 = h2;  // reuse (h2 dead after layer 3)
    float* y2 = h1;  // reuse (h1 dead after layer 2)

    dim3 blk(256);

    // encoder
    fat_gemm<0, true,  false><<<dim3(U0 / 64, BATCH / 64, FTS), blk, 0, stream>>>(x,  w1, b1, h1, BATCH, IN_DIM, U0);
    fat_gemm<0, false, false><<<dim3(U1 / 64, BATCH / 64, FTS), blk, 0, stream>>>(h1, w2, b2, h2, BATCH, U0,     U1);
    fat_gemm<0, false, false><<<dim3(DIM / 64, BATCH / 64, FTS), blk, 0, stream>>>(h2, w3, b3, h3, BATCH, U1,    DIM);
    // vector quantization (f64 distances)
    vq_kernel<<<dim3((FTS * BATCH) / 256), blk, 0, stream>>>(h3, cbk, q);
    // decoder
    fat_gemm<0, false, false><<<dim3(U1 / 64, BATCH / 64, FTS), blk, 0, stream>>>(q,  w4, b4, y1, BATCH, DIM, U1);
    fat_gemm<0, false, false><<<dim3(U0 / 64, BATCH / 64, FTS), blk, 0, stream>>>(y1, w5, b5, y2, BATCH, U1, U0);
    fat_gemm<1, false, true ><<<dim3(FTS / 64, BATCH / 64, FTS), blk, 0, stream>>>(y2, w6, b6, out, BATCH, U0, FTS);
}

// Round 3
// 1112.216 us; speedup vs baseline: 1.8226x; 1.8226x over previous
//
#include <hip/hip_runtime.h>
#include <hip/hip_bf16.h>
#include <math.h>

#define FTS 256
#define IN_DIM 255
#define U0 512
#define U1 256
#define DIM 64
#define EMB 512
#define BATCH 256

typedef __attribute__((ext_vector_type(8))) __bf16 bf16x8;
typedef __attribute__((ext_vector_type(4))) float f32x4;

__device__ __forceinline__ int swz8(int x) { return (x ^ (x >> 3)) & 7; }

// ---------------------------------------------------------------------------
// fp32 tiled GEMM (encoder layers). C[f,m,n] = relu(sum_k A[f,m,k]*W[f,k,n]+b)
// ---------------------------------------------------------------------------
template<int ACT, bool A_XLAYOUT, bool OUT_TRANS>
__global__ __launch_bounds__(256)
void fat_gemm(const float* __restrict__ A, const float* __restrict__ W,
              const float* __restrict__ bias, float* __restrict__ C,
              int M, int K, int N) {
    const int f   = blockIdx.z;
    const int bm  = blockIdx.y * 64;
    const int bn  = blockIdx.x * 64;
    const int tid = threadIdx.x;

    __shared__ float As[16][68];
    __shared__ float Bs[16][68];

    const int tx = tid & 15;
    const int ty = tid >> 4;

    float acc[4][4];
#pragma unroll
    for (int i = 0; i < 4; i++)
#pragma unroll
        for (int j = 0; j < 4; j++) acc[i][j] = 0.f;

    const float* Wf = W + (size_t)f * K * N;

    for (int k0 = 0; k0 < K; k0 += 16) {
#pragma unroll
        for (int i = 0; i < 4; i++) {
            int e = i * 256 + tid;
            int r = e >> 4, c = e & 15;
            int k = k0 + c;
            float v = 0.f;
            if (k < K) {
                size_t idx;
                if (A_XLAYOUT) idx = (size_t)(bm + r) * (FTS * IN_DIM) + (size_t)f * IN_DIM + k;
                else           idx = (size_t)f * M * K + (size_t)(bm + r) * K + k;
                v = A[idx];
            }
            As[c][r] = v;
        }
#pragma unroll
        for (int i = 0; i < 4; i++) {
            int e = i * 256 + tid;
            int c = e >> 6, j = e & 63;
            int k = k0 + c;
            float v = 0.f;
            if (k < K) v = Wf[(size_t)k * N + bn + j];
            Bs[c][j] = v;
        }
        __syncthreads();
#pragma unroll
        for (int kk = 0; kk < 16; kk++) {
            float4 a = *(const float4*)&As[kk][ty * 4];
            float4 b = *(const float4*)&Bs[kk][tx * 4];
            float av[4] = {a.x, a.y, a.z, a.w};
            float bv[4] = {b.x, b.y, b.z, b.w};
#pragma unroll
            for (int i = 0; i < 4; i++)
#pragma unroll
                for (int j = 0; j < 4; j++)
                    acc[i][j] = fmaf(av[i], bv[j], acc[i][j]);
        }
        __syncthreads();
    }

#pragma unroll
    for (int j = 0; j < 4; j++) {
        float bval = bias[(size_t)f * N + bn + tx * 4 + j];
#pragma unroll
        for (int i = 0; i < 4; i++) {
            float v = acc[i][j] + bval;
            if (ACT == 0) v = v > 0.f ? v : 0.f;
            else          v = 1.f / (1.f + expf(-v));
            int row = bm + ty * 4 + i;
            int col = bn + tx * 4 + j;
            size_t oidx;
            if (OUT_TRANS) oidx = (size_t)row * ((size_t)FTS * N) + (size_t)f * N + col;
            else           oidx = (size_t)f * M * N + (size_t)row * N + col;
            C[oidx] = v;
        }
    }
}

// ---------------------------------------------------------------------------
// VQ as f32 GEMM + argmin. 64 rows/block, 4x4 micro-tile, split accumulators
// (4 chains, 16-deep) keep distance error ~1e-5 (well under flip margin).
// ---------------------------------------------------------------------------
__global__ __launch_bounds__(256)
void vq_gemm(const float* __restrict__ h, const float* __restrict__ cbk,
             float* __restrict__ q) {
    __shared__ float Hs[64][68];     // rows x dims
    __shared__ float Cs[64 * 64];    // codes x dims, chunk-swizzled
    __shared__ float cbn_s[64];
    __shared__ int   idx_s[64];

    const int tid = threadIdx.x;
    const int tx  = tid & 15;        // code group
    const int ty  = tid >> 4;        // row group
    const int r0  = blockIdx.x * 64;

    // stage H once: 64 rows x 64 dims
    {
        int r  = tid >> 2;
        int kq = (tid & 3) * 16;
#pragma unroll
        for (int i = 0; i < 4; i++) {
            float4 v = *(const float4*)&h[(size_t)(r0 + r) * 64 + kq + i * 4];
            *(float4*)&Hs[r][kq + i * 4] = v;
        }
    }

    float best[4];
    int   bidx[4];
#pragma unroll
    for (int i = 0; i < 4; i++) { best[i] = 3.4e38f; bidx[i] = 0; }

    for (int ct = 0; ct < EMB / 64; ct++) {
        __syncthreads();
        // stage 64 codes x 64 dims, swizzled: chunk' = chunk ^ ((c>>2)&15)
        {
            int c  = tid >> 2;
            int cq = tid & 3;
#pragma unroll
            for (int cc = 0; cc < 4; cc++) {
                int chunk = cq * 4 + cc;
                float4 v = *(const float4*)&cbk[(size_t)(ct * 64 + c) * 64 + chunk * 4];
                int sw = chunk ^ ((c >> 2) & 15);
                *(float4*)&Cs[c * 64 + sw * 4] = v;
            }
        }
        __syncthreads();
        if (tid < 64) {
            int c = tid;
            float s0 = 0.f, s1 = 0.f, s2 = 0.f, s3 = 0.f;
#pragma unroll
            for (int ch = 0; ch < 16; ch++) {
                int sw = ch ^ ((c >> 2) & 15);
                float4 v = *(const float4*)&Cs[c * 64 + sw * 4];
                s0 = fmaf(v.x, v.x, s0); s1 = fmaf(v.y, v.y, s1);
                s2 = fmaf(v.z, v.z, s2); s3 = fmaf(v.w, v.w, s3);
            }
            cbn_s[c] = (s0 + s1) + (s2 + s3);
        }
        __syncthreads();

        f32x4 acc[4][4] = {};
#pragma unroll
        for (int kv = 0; kv < 16; kv++) {
            float4 a4[4], b4[4];
#pragma unroll
            for (int i = 0; i < 4; i++)
                a4[i] = *(const float4*)&Hs[ty * 4 + i][kv * 4];
#pragma unroll
            for (int j = 0; j < 4; j++) {
                int c = tx * 4 + j;
                int sw = kv ^ ((c >> 2) & 15);
                b4[j] = *(const float4*)&Cs[c * 64 + sw * 4];
            }
#pragma unroll
            for (int i = 0; i < 4; i++)
#pragma unroll
                for (int j = 0; j < 4; j++) {
                    acc[i][j][0] = fmaf(a4[i].x, b4[j].x, acc[i][j][0]);
                    acc[i][j][1] = fmaf(a4[i].y, b4[j].y, acc[i][j][1]);
                    acc[i][j][2] = fmaf(a4[i].z, b4[j].z, acc[i][j][2]);
                    acc[i][j][3] = fmaf(a4[i].w, b4[j].w, acc[i][j][3]);
                }
        }
#pragma unroll
        for (int i = 0; i < 4; i++)
#pragma unroll
            for (int j = 0; j < 4; j++) {
                int c = tx * 4 + j;
                float dot = (acc[i][j][0] + acc[i][j][1]) + (acc[i][j][2] + acc[i][j][3]);
                float dist = cbn_s[c] - 2.f * dot;
                if (dist < best[i]) { best[i] = dist; bidx[i] = ct * 64 + c; }
            }
    }

    // reduce across the 16 tx lanes (low 4 bits of lane id)
#pragma unroll
    for (int i = 0; i < 4; i++) {
#pragma unroll
        for (int mask = 1; mask < 16; mask <<= 1) {
            float od = __shfl_xor(best[i], mask, 64);
            int   oi = __shfl_xor(bidx[i], mask, 64);
            if (od < best[i] || (od == best[i] && oi < bidx[i])) {
                best[i] = od; bidx[i] = oi;
            }
        }
        if (tx == 0) idx_s[ty * 4 + i] = bidx[i];
    }
    __syncthreads();

    // cooperative gather of selected codes
    {
        int r  = tid >> 2;
        int cq = tid & 3;
        int idx = idx_s[r];
#pragma unroll
        for (int i = 0; i < 4; i++) {
            float4 v = *(const float4*)&cbk[(size_t)idx * 64 + cq * 16 + i * 4];
            *(float4*)&q[(size_t)(r0 + r) * 64 + cq * 16 + i * 4] = v;
        }
    }
}

// ---------------------------------------------------------------------------
// Decoder GEMM: bf16x2-split MFMA (hi+lo), f32 in/out, conversion fused into
// LDS staging. Tile 128x128, BK=64, 4 waves (2x2), 64x64 per wave.
// ---------------------------------------------------------------------------
template<int ACT, bool OUT_TRANS>
__global__ __launch_bounds__(256)
void dec_gemm(const float* __restrict__ A, const float* __restrict__ W,
              const float* __restrict__ bias, float* __restrict__ C,
              int M, int K, int N) {
    const int f    = blockIdx.z;
    const int bm   = blockIdx.y * 128;
    const int bn   = blockIdx.x * 128;
    const int tid  = threadIdx.x;
    const int lane = tid & 63;
    const int wv   = tid >> 6;
    const int wr   = (wv >> 1) * 64;   // wave row offset
    const int wc   = (wv & 1) * 64;    // wave col offset

    __shared__ __bf16 Ah[128 * 64];
    __shared__ __bf16 Al[128 * 64];
    __shared__ __bf16 Bh[128 * 64];
    __shared__ __bf16 Bl[128 * 64];

    f32x4 acc[4][4] = {};

    const float* Af = A + (size_t)f * M * K;
    const float* Wf = W + (size_t)f * K * N;

    for (int k0 = 0; k0 < K; k0 += 64) {
        // ---- stage A [128 m][64 k] with hi/lo split ----
        {
            const int r  = tid >> 2;
            const int kq = (tid & 3) << 4;   // 0,16,32,48
#pragma unroll
            for (int half = 0; half < 2; half++) {
                const int m = half * 64 + r;
                const float* src = Af + (size_t)(bm + m) * K + k0 + kq;
                float4 v[4];
                v[0] = *(const float4*)(src);
                v[1] = *(const float4*)(src + 4);
                v[2] = *(const float4*)(src + 8);
                v[3] = *(const float4*)(src + 12);
                const float* fv = (const float*)v;
#pragma unroll
                for (int c2 = 0; c2 < 2; c2++) {
                    bf16x8 hv, lv;
#pragma unroll
                    for (int e = 0; e < 8; e++) {
                        float x = fv[c2 * 8 + e];
                        __bf16 hb = (__bf16)x;
                        hv[e] = hb;
                        lv[e] = (__bf16)(x - (float)hb);
                    }
                    int chunk = (kq >> 3) + c2;
                    int off = m * 64 + (chunk ^ swz8(m)) * 8;
                    *(bf16x8*)&Ah[off] = hv;
                    *(bf16x8*)&Al[off] = lv;
                }
            }
        }
        // ---- stage B as [n][k] (transpose of W[k][n]) with hi/lo split ----
        {
            const int n0 = (tid & 31) << 2;  // 0..124
            const int kb = (tid >> 5) << 3;  // 0,8,...,56
            float4 rows[8];
#pragma unroll
            for (int kk = 0; kk < 8; kk++)
                rows[kk] = *(const float4*)(Wf + (size_t)(k0 + kb + kk) * N + bn + n0);
#pragma unroll
            for (int j = 0; j < 4; j++) {
                int n = n0 + j;
                bf16x8 hv, lv;
#pragma unroll
                for (int kk = 0; kk < 8; kk++) {
                    float x = ((const float*)&rows[kk])[j];
                    __bf16 hb = (__bf16)x;
                    hv[kk] = hb;
                    lv[kk] = (__bf16)(x - (float)hb);
                }
                int chunk = (kb >> 3) ^ swz8(n);
                int off = n * 64 + chunk * 8;
                *(bf16x8*)&Bh[off] = hv;
                *(bf16x8*)&Bl[off] = lv;
            }
        }
        __syncthreads();

#pragma unroll
        for (int kh = 0; kh < 2; kh++) {
            const int cb = kh * 4 + (lane >> 4);
            const int kr = lane & 15;
            bf16x8 ah[4], al[4], bhv[4], blv[4];
#pragma unroll
            for (int rb = 0; rb < 4; rb++) {
                int m = wr + rb * 16 + kr;
                int off = m * 64 + (cb ^ swz8(m)) * 8;
                ah[rb] = *(const bf16x8*)&Ah[off];
                al[rb] = *(const bf16x8*)&Al[off];
            }
#pragma unroll
            for (int nb = 0; nb < 4; nb++) {
                int n = wc + nb * 16 + kr;
                int off = n * 64 + (cb ^ swz8(n)) * 8;
                bhv[nb] = *(const bf16x8*)&Bh[off];
                blv[nb] = *(const bf16x8*)&Bl[off];
            }
#pragma unroll
            for (int rb = 0; rb < 4; rb++)
#pragma unroll
                for (int nb = 0; nb < 4; nb++) {
                    acc[rb][nb] = __builtin_amdgcn_mfma_f32_16x16x32_bf16(ah[rb], bhv[nb], acc[rb][nb], 0, 0, 0);
                    acc[rb][nb] = __builtin_amdgcn_mfma_f32_16x16x32_bf16(ah[rb], blv[nb], acc[rb][nb], 0, 0, 0);
                    acc[rb][nb] = __builtin_amdgcn_mfma_f32_16x16x32_bf16(al[rb], bhv[nb], acc[rb][nb], 0, 0, 0);
                }
        }
        __syncthreads();
    }

    // ---- epilogue ----
#pragma unroll
    for (int nb = 0; nb < 4; nb++) {
        int col = bn + wc + nb * 16 + (lane & 15);
        float bval = bias[(size_t)f * N + col];
#pragma unroll
        for (int rb = 0; rb < 4; rb++) {
#pragma unroll
            for (int j = 0; j < 4; j++) {
                int row = bm + wr + rb * 16 + (lane >> 4) * 4 + j;
                float v = acc[rb][nb][j] + bval;
                if (ACT == 0) v = v > 0.f ? v : 0.f;
                else          v = 1.f / (1.f + expf(-v));
                size_t oidx;
                if (OUT_TRANS) oidx = (size_t)row * ((size_t)FTS * FTS) + (size_t)f * N + col;
                else           oidx = (size_t)f * M * N + (size_t)row * N + col;
                C[oidx] = v;
            }
        }
    }
}

extern "C" void kernel_launch(void* const* d_in, const int* in_sizes, int n_in,
                              void* d_out, int out_size, void* d_ws, size_t ws_size,
                              hipStream_t stream) {
    const float* x   = (const float*)d_in[0];
    const float* w1  = (const float*)d_in[1];
    const float* b1  = (const float*)d_in[2];
    const float* w2  = (const float*)d_in[3];
    const float* b2  = (const float*)d_in[4];
    const float* w3  = (const float*)d_in[5];
    const float* b3  = (const float*)d_in[6];
    const float* cbk = (const float*)d_in[7];
    const float* w4  = (const float*)d_in[8];
    const float* b4  = (const float*)d_in[9];
    const float* w5  = (const float*)d_in[10];
    const float* b5  = (const float*)d_in[11];
    const float* w6  = (const float*)d_in[12];
    const float* b6  = (const float*)d_in[13];
    float* out = (float*)d_out;

    float* ws = (float*)d_ws;
    float* h1 = ws;                                   // [256,256,512]
    float* h2 = h1 + (size_t)FTS * BATCH * U0;        // [256,256,256]
    float* h3 = h2 + (size_t)FTS * BATCH * U1;        // [256,256, 64]
    float* q  = h3 + (size_t)FTS * BATCH * DIM;       // [256,256, 64]
    float* y1 = h2;  // reuse
    float* y2 = h1;  // reuse

    dim3 blk(256);

    // encoder (fp32)
    fat_gemm<0, true,  false><<<dim3(U0 / 64, BATCH / 64, FTS), blk, 0, stream>>>(x,  w1, b1, h1, BATCH, IN_DIM, U0);
    fat_gemm<0, false, false><<<dim3(U1 / 64, BATCH / 64, FTS), blk, 0, stream>>>(h1, w2, b2, h2, BATCH, U0,     U1);
    fat_gemm<0, false, false><<<dim3(DIM / 64, BATCH / 64, FTS), blk, 0, stream>>>(h2, w3, b3, h3, BATCH, U1,    DIM);
    // vector quantization (f32 GEMM-structured, split accumulators)
    vq_gemm<<<dim3((FTS * BATCH) / 64), blk, 0, stream>>>(h3, cbk, q);
    // decoder (bf16x2 split MFMA)
    dec_gemm<0, false><<<dim3(U1 / 128, BATCH / 128, FTS), blk, 0, stream>>>(q,  w4, b4, y1, BATCH, DIM, U1);
    dec_gemm<0, false><<<dim3(U0 / 128, BATCH / 128, FTS), blk, 0, stream>>>(y1, w5, b5, y2, BATCH, U1, U0);
    dec_gemm<1, true ><<<dim3(FTS / 128, BATCH / 128, FTS), blk, 0, stream>>>(y2, w6, b6, out, BATCH, U0, FTS);
}

// Round 4
// 864.686 us; speedup vs baseline: 2.3443x; 1.2863x over previous
//
#include <hip/hip_runtime.h>
#include <hip/hip_bf16.h>
#include <math.h>

#define FTS 256
#define IN_DIM 255
#define U0 512
#define U1 256
#define DIM 64
#define EMB 512
#define BATCH 256

typedef __attribute__((ext_vector_type(8))) __bf16 bf16x8;
typedef __attribute__((ext_vector_type(4))) float f32x4;
typedef _Float16 half8 __attribute__((ext_vector_type(8)));

__device__ __forceinline__ int swz8(int x) { return (x ^ (x >> 3)) & 7; }

// ---------------------------------------------------------------------------
// split_x: x [b][f][255] f32 -> Xh/Xl [f][b][256] fp16 (lo scaled by 4096),
// zero-padded at k=255.
// ---------------------------------------------------------------------------
__global__ __launch_bounds__(256)
void split_x(const float* __restrict__ x, _Float16* __restrict__ Xh,
             _Float16* __restrict__ Xl) {
    const int R = blockIdx.x * 4 + (threadIdx.x >> 6);  // R = f*256+b
    const int f = R >> 8, b = R & 255;
    const int kq = (threadIdx.x & 63) * 4;
    const float* src = x + ((size_t)b * FTS + f) * IN_DIM;
    _Float16 hb[4], lb[4];
#pragma unroll
    for (int i = 0; i < 4; i++) {
        int k = kq + i;
        float v = (k < IN_DIM) ? src[k] : 0.f;
        _Float16 h = (_Float16)v;
        hb[i] = h;
        lb[i] = (_Float16)((v - (float)h) * 4096.f);
    }
    size_t o = ((size_t)f * BATCH + b) * 256 + kq;
    *(uint2*)(Xh + o) = *(uint2*)hb;
    *(uint2*)(Xl + o) = *(uint2*)lb;
}

// ---------------------------------------------------------------------------
// split_wT: w [f][K][N] f32 -> Wh/Wl [f][N][Kpad] fp16 (transposed, lo*4096),
// zero-padded for k >= K.
// ---------------------------------------------------------------------------
__global__ __launch_bounds__(256)
void split_wT(const float* __restrict__ w, _Float16* __restrict__ Wh,
              _Float16* __restrict__ Wl, int K, int N, int Kpad) {
    const int f  = blockIdx.z;
    const int k0 = blockIdx.y * 64;
    const int n0 = blockIdx.x * 64;
    const int tid = threadIdx.x;
    __shared__ float sT[64][65];
    {
        const int c4 = (tid & 15) * 4;
#pragma unroll
        for (int p = 0; p < 4; p++) {
            int kk = (tid >> 4) + p * 16;
            int k = k0 + kk;
            float4 v = {0.f, 0.f, 0.f, 0.f};
            if (k < K) v = *(const float4*)(w + ((size_t)f * K + k) * N + n0 + c4);
            sT[kk][c4 + 0] = v.x; sT[kk][c4 + 1] = v.y;
            sT[kk][c4 + 2] = v.z; sT[kk][c4 + 3] = v.w;
        }
    }
    __syncthreads();
    {
        const int n  = tid >> 2;
        const int kb = (tid & 3) * 16;
        _Float16 hbuf[16], lbuf[16];
#pragma unroll
        for (int i = 0; i < 16; i++) {
            float v = sT[kb + i][n];
            _Float16 h = (_Float16)v;
            hbuf[i] = h;
            lbuf[i] = (_Float16)((v - (float)h) * 4096.f);
        }
        size_t o = ((size_t)f * N + n0 + n) * Kpad + k0 + kb;
        *(uint4*)(Wh + o)     = *(uint4*)hbuf;
        *(uint4*)(Wh + o + 8) = *(uint4*)(hbuf + 8);
        *(uint4*)(Wl + o)     = *(uint4*)lbuf;
        *(uint4*)(Wl + o + 8) = *(uint4*)(lbuf + 8);
    }
}

// ---------------------------------------------------------------------------
// enc_gemm: fp32-accurate GEMM via scaled fp16 2-split, 3 MFMAs per product.
// A: [f][M][K] splits, B: [f][N][K] splits (pre-transposed). Tile 128xBN,
// BK=32, 4 waves 2x2. relu epilogue; SPLIT_OUT writes fp16 splits, else f32.
// ---------------------------------------------------------------------------
template<int BN, bool SPLIT_OUT>
__global__ __launch_bounds__(256)
void enc_gemm(const _Float16* __restrict__ Ah, const _Float16* __restrict__ Al,
              const _Float16* __restrict__ Bh, const _Float16* __restrict__ Bl,
              const float* __restrict__ bias,
              _Float16* __restrict__ Ch, _Float16* __restrict__ Cl,
              float* __restrict__ Cf, int M, int K, int N) {
    constexpr int NB = BN / 32;       // n-frags per wave
    const int f   = blockIdx.z;
    const int bm  = blockIdx.y * 128;
    const int bn  = blockIdx.x * BN;
    const int tid = threadIdx.x, lane = tid & 63, wv = tid >> 6;
    const int wr  = (wv >> 1) * 64;
    const int wc  = (wv & 1) * (BN / 2);

    // row stride 40 halves (80B): 16B-aligned rows, 2-way (free) bank aliasing
    __shared__ _Float16 sAh[128 * 40], sAl[128 * 40];
    __shared__ _Float16 sBh[BN * 40],  sBl[BN * 40];

    f32x4 acc[4][NB] = {};  // ah*bh
    f32x4 acx[4][NB] = {};  // ah*bl + al*bh (scale 2^12)

    const _Float16* pAh = Ah + (size_t)f * M * K;
    const _Float16* pAl = Al + (size_t)f * M * K;
    const _Float16* pBh = Bh + (size_t)f * N * K;
    const _Float16* pBl = Bl + (size_t)f * N * K;

    for (int k0 = 0; k0 < K; k0 += 32) {
#pragma unroll
        for (int j = 0; j < 2; j++) {
            int l = j * 256 + tid;
            int m = l >> 2, cb = l & 3;
            size_t g = (size_t)(bm + m) * K + k0 + cb * 8;
            *(uint4*)&sAh[m * 40 + cb * 8] = *(const uint4*)(pAh + g);
            *(uint4*)&sAl[m * 40 + cb * 8] = *(const uint4*)(pAl + g);
        }
#pragma unroll
        for (int j = 0; j < BN / 64; j++) {
            int l = j * 256 + tid;
            int n = l >> 2, cb = l & 3;
            size_t g = (size_t)(bn + n) * K + k0 + cb * 8;
            *(uint4*)&sBh[n * 40 + cb * 8] = *(const uint4*)(pBh + g);
            *(uint4*)&sBl[n * 40 + cb * 8] = *(const uint4*)(pBl + g);
        }
        __syncthreads();

        const int kr = lane & 15, kg = lane >> 4;
        half8 fah[4], fal[4], fbh[NB], fbl[NB];
#pragma unroll
        for (int rb = 0; rb < 4; rb++) {
            int off = (wr + rb * 16 + kr) * 40 + kg * 8;
            fah[rb] = *(const half8*)&sAh[off];
            fal[rb] = *(const half8*)&sAl[off];
        }
#pragma unroll
        for (int nb = 0; nb < NB; nb++) {
            int off = (wc + nb * 16 + kr) * 40 + kg * 8;
            fbh[nb] = *(const half8*)&sBh[off];
            fbl[nb] = *(const half8*)&sBl[off];
        }
#pragma unroll
        for (int rb = 0; rb < 4; rb++)
#pragma unroll
            for (int nb = 0; nb < NB; nb++) {
                acc[rb][nb] = __builtin_amdgcn_mfma_f32_16x16x32_f16(fah[rb], fbh[nb], acc[rb][nb], 0, 0, 0);
                acx[rb][nb] = __builtin_amdgcn_mfma_f32_16x16x32_f16(fah[rb], fbl[nb], acx[rb][nb], 0, 0, 0);
                acx[rb][nb] = __builtin_amdgcn_mfma_f32_16x16x32_f16(fal[rb], fbh[nb], acx[rb][nb], 0, 0, 0);
            }
        __syncthreads();
    }

#pragma unroll
    for (int nb = 0; nb < NB; nb++) {
        int col = bn + wc + nb * 16 + (lane & 15);
        float bval = bias[(size_t)f * N + col];
#pragma unroll
        for (int rb = 0; rb < 4; rb++) {
#pragma unroll
            for (int jj = 0; jj < 4; jj++) {
                int row = bm + wr + rb * 16 + (lane >> 4) * 4 + jj;
                float v = acc[rb][nb][jj] + acx[rb][nb][jj] * (1.0f / 4096.0f) + bval;
                v = v > 0.f ? v : 0.f;
                size_t o = ((size_t)f * M + row) * N + col;
                if (SPLIT_OUT) {
                    _Float16 h = (_Float16)v;
                    Ch[o] = h;
                    Cl[o] = (_Float16)((v - (float)h) * 4096.f);
                } else {
                    Cf[o] = v;
                }
            }
        }
    }
}

// ---------------------------------------------------------------------------
// VQ as f32 GEMM + argmin (unchanged from round 3, passing).
// ---------------------------------------------------------------------------
__global__ __launch_bounds__(256)
void vq_gemm(const float* __restrict__ h, const float* __restrict__ cbk,
             float* __restrict__ q) {
    __shared__ float Hs[64][68];
    __shared__ float Cs[64 * 64];
    __shared__ float cbn_s[64];
    __shared__ int   idx_s[64];

    const int tid = threadIdx.x;
    const int tx  = tid & 15;
    const int ty  = tid >> 4;
    const int r0  = blockIdx.x * 64;

    {
        int r  = tid >> 2;
        int kq = (tid & 3) * 16;
#pragma unroll
        for (int i = 0; i < 4; i++) {
            float4 v = *(const float4*)&h[(size_t)(r0 + r) * 64 + kq + i * 4];
            *(float4*)&Hs[r][kq + i * 4] = v;
        }
    }

    float best[4];
    int   bidx[4];
#pragma unroll
    for (int i = 0; i < 4; i++) { best[i] = 3.4e38f; bidx[i] = 0; }

    for (int ct = 0; ct < EMB / 64; ct++) {
        __syncthreads();
        {
            int c  = tid >> 2;
            int cq = tid & 3;
#pragma unroll
            for (int cc = 0; cc < 4; cc++) {
                int chunk = cq * 4 + cc;
                float4 v = *(const float4*)&cbk[(size_t)(ct * 64 + c) * 64 + chunk * 4];
                int sw = chunk ^ ((c >> 2) & 15);
                *(float4*)&Cs[c * 64 + sw * 4] = v;
            }
        }
        __syncthreads();
        if (tid < 64) {
            int c = tid;
            float s0 = 0.f, s1 = 0.f, s2 = 0.f, s3 = 0.f;
#pragma unroll
            for (int ch = 0; ch < 16; ch++) {
                int sw = ch ^ ((c >> 2) & 15);
                float4 v = *(const float4*)&Cs[c * 64 + sw * 4];
                s0 = fmaf(v.x, v.x, s0); s1 = fmaf(v.y, v.y, s1);
                s2 = fmaf(v.z, v.z, s2); s3 = fmaf(v.w, v.w, s3);
            }
            cbn_s[c] = (s0 + s1) + (s2 + s3);
        }
        __syncthreads();

        f32x4 acc[4][4] = {};
#pragma unroll
        for (int kv = 0; kv < 16; kv++) {
            float4 a4[4], b4[4];
#pragma unroll
            for (int i = 0; i < 4; i++)
                a4[i] = *(const float4*)&Hs[ty * 4 + i][kv * 4];
#pragma unroll
            for (int j = 0; j < 4; j++) {
                int c = tx * 4 + j;
                int sw = kv ^ ((c >> 2) & 15);
                b4[j] = *(const float4*)&Cs[c * 64 + sw * 4];
            }
#pragma unroll
            for (int i = 0; i < 4; i++)
#pragma unroll
                for (int j = 0; j < 4; j++) {
                    acc[i][j][0] = fmaf(a4[i].x, b4[j].x, acc[i][j][0]);
                    acc[i][j][1] = fmaf(a4[i].y, b4[j].y, acc[i][j][1]);
                    acc[i][j][2] = fmaf(a4[i].z, b4[j].z, acc[i][j][2]);
                    acc[i][j][3] = fmaf(a4[i].w, b4[j].w, acc[i][j][3]);
                }
        }
#pragma unroll
        for (int i = 0; i < 4; i++)
#pragma unroll
            for (int j = 0; j < 4; j++) {
                int c = tx * 4 + j;
                float dot = (acc[i][j][0] + acc[i][j][1]) + (acc[i][j][2] + acc[i][j][3]);
                float dist = cbn_s[c] - 2.f * dot;
                if (dist < best[i]) { best[i] = dist; bidx[i] = ct * 64 + c; }
            }
    }

#pragma unroll
    for (int i = 0; i < 4; i++) {
#pragma unroll
        for (int mask = 1; mask < 16; mask <<= 1) {
            float od = __shfl_xor(best[i], mask, 64);
            int   oi = __shfl_xor(bidx[i], mask, 64);
            if (od < best[i] || (od == best[i] && oi < bidx[i])) {
                best[i] = od; bidx[i] = oi;
            }
        }
        if (tx == 0) idx_s[ty * 4 + i] = bidx[i];
    }
    __syncthreads();

    {
        int r  = tid >> 2;
        int cq = tid & 3;
        int idx = idx_s[r];
#pragma unroll
        for (int i = 0; i < 4; i++) {
            float4 v = *(const float4*)&cbk[(size_t)idx * 64 + cq * 16 + i * 4];
            *(float4*)&q[(size_t)(r0 + r) * 64 + cq * 16 + i * 4] = v;
        }
    }
}

// ---------------------------------------------------------------------------
// Decoder GEMM: bf16x2-split MFMA (unchanged from round 3, passing).
// ---------------------------------------------------------------------------
template<int ACT, bool OUT_TRANS>
__global__ __launch_bounds__(256)
void dec_gemm(const float* __restrict__ A, const float* __restrict__ W,
              const float* __restrict__ bias, float* __restrict__ C,
              int M, int K, int N) {
    const int f    = blockIdx.z;
    const int bm   = blockIdx.y * 128;
    const int bn   = blockIdx.x * 128;
    const int tid  = threadIdx.x;
    const int lane = tid & 63;
    const int wv   = tid >> 6;
    const int wr   = (wv >> 1) * 64;
    const int wc   = (wv & 1) * 64;

    __shared__ __bf16 Ahs[128 * 64];
    __shared__ __bf16 Als[128 * 64];
    __shared__ __bf16 Bhs[128 * 64];
    __shared__ __bf16 Bls[128 * 64];

    f32x4 acc[4][4] = {};

    const float* Af = A + (size_t)f * M * K;
    const float* Wf = W + (size_t)f * K * N;

    for (int k0 = 0; k0 < K; k0 += 64) {
        {
            const int r  = tid >> 2;
            const int kq = (tid & 3) << 4;
#pragma unroll
            for (int half = 0; half < 2; half++) {
                const int m = half * 64 + r;
                const float* src = Af + (size_t)(bm + m) * K + k0 + kq;
                float4 v[4];
                v[0] = *(const float4*)(src);
                v[1] = *(const float4*)(src + 4);
                v[2] = *(const float4*)(src + 8);
                v[3] = *(const float4*)(src + 12);
                const float* fv = (const float*)v;
#pragma unroll
                for (int c2 = 0; c2 < 2; c2++) {
                    bf16x8 hv, lv;
#pragma unroll
                    for (int e = 0; e < 8; e++) {
                        float xx = fv[c2 * 8 + e];
                        __bf16 hb = (__bf16)xx;
                        hv[e] = hb;
                        lv[e] = (__bf16)(xx - (float)hb);
                    }
                    int chunk = (kq >> 3) + c2;
                    int off = m * 64 + (chunk ^ swz8(m)) * 8;
                    *(bf16x8*)&Ahs[off] = hv;
                    *(bf16x8*)&Als[off] = lv;
                }
            }
        }
        {
            const int n0 = (tid & 31) << 2;
            const int kb = (tid >> 5) << 3;
            float4 rows[8];
#pragma unroll
            for (int kk = 0; kk < 8; kk++)
                rows[kk] = *(const float4*)(Wf + (size_t)(k0 + kb + kk) * N + bn + n0);
#pragma unroll
            for (int j = 0; j < 4; j++) {
                int n = n0 + j;
                bf16x8 hv, lv;
#pragma unroll
                for (int kk = 0; kk < 8; kk++) {
                    float xx = ((const float*)&rows[kk])[j];
                    __bf16 hb = (__bf16)xx;
                    hv[kk] = hb;
                    lv[kk] = (__bf16)(xx - (float)hb);
                }
                int chunk = (kb >> 3) ^ swz8(n);
                int off = n * 64 + chunk * 8;
                *(bf16x8*)&Bhs[off] = hv;
                *(bf16x8*)&Bls[off] = lv;
            }
        }
        __syncthreads();

#pragma unroll
        for (int kh = 0; kh < 2; kh++) {
            const int cb = kh * 4 + (lane >> 4);
            const int kr = lane & 15;
            bf16x8 ah[4], al[4], bhv[4], blv[4];
#pragma unroll
            for (int rb = 0; rb < 4; rb++) {
                int m = wr + rb * 16 + kr;
                int off = m * 64 + (cb ^ swz8(m)) * 8;
                ah[rb] = *(const bf16x8*)&Ahs[off];
                al[rb] = *(const bf16x8*)&Als[off];
            }
#pragma unroll
            for (int nb = 0; nb < 4; nb++) {
                int n = wc + nb * 16 + kr;
                int off = n * 64 + (cb ^ swz8(n)) * 8;
                bhv[nb] = *(const bf16x8*)&Bhs[off];
                blv[nb] = *(const bf16x8*)&Bls[off];
            }
#pragma unroll
            for (int rb = 0; rb < 4; rb++)
#pragma unroll
                for (int nb = 0; nb < 4; nb++) {
                    acc[rb][nb] = __builtin_amdgcn_mfma_f32_16x16x32_bf16(ah[rb], bhv[nb], acc[rb][nb], 0, 0, 0);
                    acc[rb][nb] = __builtin_amdgcn_mfma_f32_16x16x32_bf16(ah[rb], blv[nb], acc[rb][nb], 0, 0, 0);
                    acc[rb][nb] = __builtin_amdgcn_mfma_f32_16x16x32_bf16(al[rb], bhv[nb], acc[rb][nb], 0, 0, 0);
                }
        }
        __syncthreads();
    }

#pragma unroll
    for (int nb = 0; nb < 4; nb++) {
        int col = bn + wc + nb * 16 + (lane & 15);
        float bval = bias[(size_t)f * N + col];
#pragma unroll
        for (int rb = 0; rb < 4; rb++) {
#pragma unroll
            for (int j = 0; j < 4; j++) {
                int row = bm + wr + rb * 16 + (lane >> 4) * 4 + j;
                float v = acc[rb][nb][j] + bval;
                if (ACT == 0) v = v > 0.f ? v : 0.f;
                else          v = 1.f / (1.f + expf(-v));
                size_t oidx;
                if (OUT_TRANS) oidx = (size_t)row * ((size_t)FTS * FTS) + (size_t)f * N + col;
                else           oidx = (size_t)f * M * N + (size_t)row * N + col;
                C[oidx] = v;
            }
        }
    }
}

extern "C" void kernel_launch(void* const* d_in, const int* in_sizes, int n_in,
                              void* d_out, int out_size, void* d_ws, size_t ws_size,
                              hipStream_t stream) {
    const float* x   = (const float*)d_in[0];
    const float* w1  = (const float*)d_in[1];
    const float* b1  = (const float*)d_in[2];
    const float* w2  = (const float*)d_in[3];
    const float* b2  = (const float*)d_in[4];
    const float* w3  = (const float*)d_in[5];
    const float* b3  = (const float*)d_in[6];
    const float* cbk = (const float*)d_in[7];
    const float* w4  = (const float*)d_in[8];
    const float* b4  = (const float*)d_in[9];
    const float* w5  = (const float*)d_in[10];
    const float* b5  = (const float*)d_in[11];
    const float* w6  = (const float*)d_in[12];
    const float* b6  = (const float*)d_in[13];
    float* out = (float*)d_out;

    // ---- workspace overlay (total ~352 MiB) ----
    char* W = (char*)d_ws;
    // R_w: 128 MiB, reused for w1 -> w2 -> w3 splits, then y1 (f32)
    _Float16* Wsh = (_Float16*)W;
    _Float16* Wsl = Wsh + (size_t)33554432;            // 256*512*256
    char* p = W + (size_t)134217728;
    // R_x: 64 MiB: x splits, then h2 splits
    _Float16* Xh = (_Float16*)p;
    _Float16* Xl = Xh + (size_t)16777216;              // 256*256*256
    p += (size_t)67108864;
    // R_h1: 128 MiB: h1 splits, then y2 (f32)
    _Float16* H1h = (_Float16*)p;
    _Float16* H1l = H1h + (size_t)33554432;            // 256*256*512
    p += (size_t)134217728;
    // R_small: h3 + q (f32)
    float* h3 = (float*)p;
    float* q  = h3 + (size_t)4194304;                  // 256*256*64
    // overlays
    _Float16* H2h = Xh;
    _Float16* H2l = Xl;
    float* y1 = (float*)W;
    float* y2 = (float*)H1h;

    dim3 blk(256);

    // ---- encoder: split-convert + fp16-2split MFMA GEMMs ----
    split_x<<<dim3(16384), blk, 0, stream>>>(x, Xh, Xl);
    split_wT<<<dim3(8, 4, 256), blk, 0, stream>>>(w1, Wsh, Wsl, IN_DIM, U0, 256);
    enc_gemm<128, true><<<dim3(4, 2, 256), blk, 0, stream>>>(
        Xh, Xl, Wsh, Wsl, b1, H1h, H1l, nullptr, BATCH, 256, U0);
    split_wT<<<dim3(4, 8, 256), blk, 0, stream>>>(w2, Wsh, Wsl, U0, U1, 512);
    enc_gemm<128, true><<<dim3(2, 2, 256), blk, 0, stream>>>(
        H1h, H1l, Wsh, Wsl, b2, H2h, H2l, nullptr, BATCH, 512, U1);
    split_wT<<<dim3(1, 4, 256), blk, 0, stream>>>(w3, Wsh, Wsl, U1, DIM, 256);
    enc_gemm<64, false><<<dim3(1, 2, 256), blk, 0, stream>>>(
        H2h, H2l, Wsh, Wsl, b3, nullptr, nullptr, h3, BATCH, 256, DIM);

    // ---- vector quantization ----
    vq_gemm<<<dim3((FTS * BATCH) / 64), blk, 0, stream>>>(h3, cbk, q);

    // ---- decoder (bf16x2 split MFMA) ----
    dec_gemm<0, false><<<dim3(U1 / 128, BATCH / 128, FTS), blk, 0, stream>>>(q,  w4, b4, y1, BATCH, DIM, U1);
    dec_gemm<0, false><<<dim3(U0 / 128, BATCH / 128, FTS), blk, 0, stream>>>(y1, w5, b5, y2, BATCH, U1, U0);
    dec_gemm<1, true ><<<dim3(FTS / 128, BATCH / 128, FTS), blk, 0, stream>>>(y2, w6, b6, out, BATCH, U0, FTS);
}

// Round 6
// 739.919 us; speedup vs baseline: 2.7396x; 1.1686x over previous
//
#include <hip/hip_runtime.h>
#include <hip/hip_bf16.h>
#include <math.h>

#define FTS 256
#define IN_DIM 255
#define U0 512
#define U1 256
#define DIM 64
#define EMB 512
#define BATCH 256

typedef __attribute__((ext_vector_type(4))) float f32x4;
typedef _Float16 half8 __attribute__((ext_vector_type(8)));

__device__ __forceinline__ int swz8(int x) { return (x ^ (x >> 3)) & 7; }

// ---------------------------------------------------------------------------
// split_x: x [b][f][255] f32 -> Xh/Xl [f][b][256] fp16 (lo scaled by 4096),
// zero-padded at k=255. (handles misaligned strided gather)
// ---------------------------------------------------------------------------
__global__ __launch_bounds__(256)
void split_x(const float* __restrict__ x, _Float16* __restrict__ Xh,
             _Float16* __restrict__ Xl) {
    const int R = blockIdx.x * 4 + (threadIdx.x >> 6);  // R = f*256+b
    const int f = R >> 8, b = R & 255;
    const int kq = (threadIdx.x & 63) * 4;
    const float* src = x + ((size_t)b * FTS + f) * IN_DIM;
    _Float16 hb[4], lb[4];
#pragma unroll
    for (int i = 0; i < 4; i++) {
        int k = kq + i;
        float v = (k < IN_DIM) ? src[k] : 0.f;
        _Float16 h = (_Float16)v;
        hb[i] = h;
        lb[i] = (_Float16)((v - (float)h) * 4096.f);
    }
    size_t o = ((size_t)f * BATCH + b) * 256 + kq;
    *(uint2*)(Xh + o) = *(uint2*)hb;
    *(uint2*)(Xl + o) = *(uint2*)lb;
}

// ---------------------------------------------------------------------------
// cbk_prep: codebook [512][64] f32 -> fp16 splits [512][64] + f64 norms (f32 out)
// ---------------------------------------------------------------------------
__global__ __launch_bounds__(256)
void cbk_prep(const float* __restrict__ cbk, _Float16* __restrict__ Ckh,
              _Float16* __restrict__ Ckl, float* __restrict__ cbn) {
    const int c = blockIdx.x * 256 + threadIdx.x;
    if (c >= EMB) return;
    const float* src = cbk + (size_t)c * 64;
    double s = 0.0;
#pragma unroll
    for (int i = 0; i < 8; i++) {
        float4 v0 = *(const float4*)(src + i * 8);
        float4 v1 = *(const float4*)(src + i * 8 + 4);
        float fv[8] = {v0.x, v0.y, v0.z, v0.w, v1.x, v1.y, v1.z, v1.w};
        _Float16 hv[8], lv[8];
#pragma unroll
        for (int e = 0; e < 8; e++) {
            float xx = fv[e];
            _Float16 hb = (_Float16)xx;
            hv[e] = hb;
            lv[e] = (_Float16)((xx - (float)hb) * 4096.f);
            s = fma((double)xx, (double)xx, s);
        }
        *(uint4*)(Ckh + (size_t)c * 64 + i * 8) = *(uint4*)hv;
        *(uint4*)(Ckl + (size_t)c * 64 + i * 8) = *(uint4*)lv;
    }
    cbn[c] = (float)s;
}

// ---------------------------------------------------------------------------
// Unified fp32-accurate GEMM via scaled fp16 2-split, 3 MFMAs per product.
// A: pre-split fp16 [f][M][K] (PRESPLIT) or f32 [f][M][K] (split in staging).
// W: f32 [f][KW][N] (true k-extent KW <= K; k >= KW reads as 0),
// split+transposed in staging. Tile 128xBN, BK=64, 4 waves.
// ---------------------------------------------------------------------------
template<int ACT, int BN, bool PRESPLIT, bool OUT_TRANS>
__global__ __launch_bounds__(256)
void sgemm(const _Float16* __restrict__ Ah, const _Float16* __restrict__ Al,
           const float* __restrict__ Af, const float* __restrict__ W,
           const float* __restrict__ bias, float* __restrict__ C,
           int M, int K, int KW, int N) {
    constexpr int RB = (BN == 128) ? 4 : 2;
    const int f    = blockIdx.z;
    const int bm   = blockIdx.y * 128;
    const int bn   = blockIdx.x * BN;
    const int tid  = threadIdx.x;
    const int lane = tid & 63;
    const int wv   = tid >> 6;
    const int wr   = (BN == 128) ? (wv >> 1) * 64 : wv * 32;
    const int wc   = (BN == 128) ? (wv & 1) * 64 : 0;
    const int kr   = lane & 15;
    const int kg   = lane >> 4;

    __shared__ _Float16 sAh[128 * 64], sAl[128 * 64];
    __shared__ _Float16 sBh[BN * 64],  sBl[BN * 64];

    f32x4 acc[RB][4] = {};
    f32x4 acx[RB][4] = {};

    const float* Wf = W + (size_t)f * KW * N;   // true W stride: KW rows

    for (int k0 = 0; k0 < K; k0 += 64) {
        // ---- stage A: 128 rows x 64 k (fp16 hi/lo, chunk-swizzled) ----
        {
            const int m  = tid >> 1;
            const int q2 = (tid & 1) * 32;
            if (PRESPLIT) {
                const _Float16* p1 = Ah + ((size_t)f * M + bm + m) * K + k0 + q2;
                const _Float16* p2 = Al + ((size_t)f * M + bm + m) * K + k0 + q2;
#pragma unroll
                for (int i = 0; i < 4; i++) {
                    int dst = m * 64 + (((q2 >> 3) + i) ^ swz8(m)) * 8;
                    *(uint4*)&sAh[dst] = *(const uint4*)(p1 + i * 8);
                    *(uint4*)&sAl[dst] = *(const uint4*)(p2 + i * 8);
                }
            } else {
                const float* src = Af + ((size_t)f * M + bm + m) * K + k0 + q2;
                float fv[32];
#pragma unroll
                for (int i = 0; i < 8; i++)
                    *(float4*)&fv[i * 4] = *(const float4*)(src + i * 4);
#pragma unroll
                for (int c2 = 0; c2 < 4; c2++) {
                    _Float16 hv[8], lv[8];
#pragma unroll
                    for (int e = 0; e < 8; e++) {
                        float xx = fv[c2 * 8 + e];
                        _Float16 hb = (_Float16)xx;
                        hv[e] = hb;
                        lv[e] = (_Float16)((xx - (float)hb) * 4096.f);
                    }
                    int dst = m * 64 + (((q2 >> 3) + c2) ^ swz8(m)) * 8;
                    *(uint4*)&sAh[dst] = *(uint4*)hv;
                    *(uint4*)&sAl[dst] = *(uint4*)lv;
                }
            }
        }
        // ---- stage B: transpose W[k][n] -> [n][k] with fp16 hi/lo split ----
        if (BN == 128) {
            const int n0 = (tid & 31) * 4;
            const int kb = (tid >> 5) * 8;
            float4 rows[8];
#pragma unroll
            for (int kk = 0; kk < 8; kk++) {
                int k = k0 + kb + kk;
                rows[kk] = (k < KW) ? *(const float4*)(Wf + (size_t)k * N + bn + n0)
                                    : float4{0.f, 0.f, 0.f, 0.f};
            }
#pragma unroll
            for (int j = 0; j < 4; j++) {
                int n = n0 + j;
                _Float16 hv[8], lv[8];
#pragma unroll
                for (int kk = 0; kk < 8; kk++) {
                    float xx = ((const float*)&rows[kk])[j];
                    _Float16 hb = (_Float16)xx;
                    hv[kk] = hb;
                    lv[kk] = (_Float16)((xx - (float)hb) * 4096.f);
                }
                int dst = n * 64 + ((kb >> 3) ^ swz8(n)) * 8;
                *(uint4*)&sBh[dst] = *(uint4*)hv;
                *(uint4*)&sBl[dst] = *(uint4*)lv;
            }
        } else {
            const int n0 = (tid & 15) * 4;
            const int kb = (tid >> 4) * 4;
            float4 rows[4];
#pragma unroll
            for (int kk = 0; kk < 4; kk++) {
                int k = k0 + kb + kk;
                rows[kk] = (k < KW) ? *(const float4*)(Wf + (size_t)k * N + bn + n0)
                                    : float4{0.f, 0.f, 0.f, 0.f};
            }
#pragma unroll
            for (int j = 0; j < 4; j++) {
                int n = n0 + j;
                _Float16 hv[4], lv[4];
#pragma unroll
                for (int kk = 0; kk < 4; kk++) {
                    float xx = ((const float*)&rows[kk])[j];
                    _Float16 hb = (_Float16)xx;
                    hv[kk] = hb;
                    lv[kk] = (_Float16)((xx - (float)hb) * 4096.f);
                }
                int dst = n * 64 + ((kb >> 3) ^ swz8(n)) * 8 + (kb & 7);
                *(uint2*)&sBh[dst] = *(uint2*)hv;
                *(uint2*)&sBl[dst] = *(uint2*)lv;
            }
        }
        __syncthreads();

#pragma unroll
        for (int kh = 0; kh < 2; kh++) {
            const int cb = kh * 4 + kg;
            half8 ah[RB], al[RB], bh[4], bl[4];
#pragma unroll
            for (int rb = 0; rb < RB; rb++) {
                int m = wr + rb * 16 + kr;
                int off = m * 64 + (cb ^ swz8(m)) * 8;
                ah[rb] = *(const half8*)&sAh[off];
                al[rb] = *(const half8*)&sAl[off];
            }
#pragma unroll
            for (int nb = 0; nb < 4; nb++) {
                int n = wc + nb * 16 + kr;
                int off = n * 64 + (cb ^ swz8(n)) * 8;
                bh[nb] = *(const half8*)&sBh[off];
                bl[nb] = *(const half8*)&sBl[off];
            }
#pragma unroll
            for (int rb = 0; rb < RB; rb++)
#pragma unroll
                for (int nb = 0; nb < 4; nb++) {
                    acc[rb][nb] = __builtin_amdgcn_mfma_f32_16x16x32_f16(ah[rb], bh[nb], acc[rb][nb], 0, 0, 0);
                    acx[rb][nb] = __builtin_amdgcn_mfma_f32_16x16x32_f16(ah[rb], bl[nb], acx[rb][nb], 0, 0, 0);
                    acx[rb][nb] = __builtin_amdgcn_mfma_f32_16x16x32_f16(al[rb], bh[nb], acx[rb][nb], 0, 0, 0);
                }
        }
        __syncthreads();
    }

    // ---- epilogue ----
#pragma unroll
    for (int nb = 0; nb < 4; nb++) {
        int col = bn + wc + nb * 16 + kr;
        float bval = bias[(size_t)f * N + col];
#pragma unroll
        for (int rb = 0; rb < RB; rb++) {
#pragma unroll
            for (int j = 0; j < 4; j++) {
                int row = bm + wr + rb * 16 + kg * 4 + j;
                float v = acc[rb][nb][j] + acx[rb][nb][j] * (1.0f / 4096.0f) + bval;
                if (ACT == 0) v = v > 0.f ? v : 0.f;
                else          v = 1.f / (1.f + expf(-v));
                size_t oidx;
                if (OUT_TRANS) oidx = (size_t)row * ((size_t)FTS * FTS) + (size_t)f * N + col;
                else           oidx = (size_t)f * M * N + (size_t)row * N + col;
                C[oidx] = v;
            }
        }
    }
}

// ---------------------------------------------------------------------------
// VQ via fp16-split MFMA. 128 rows/block, 8 code-tiles of 64.
// dist = ||c||^2 - 2*(acc + acx/4096); per-lane running best over C-fragment
// layout; shfl_xor reduce over same-row lanes; LDS merge across code halves.
// ---------------------------------------------------------------------------
__global__ __launch_bounds__(256)
void vq_mfma(const float* __restrict__ h, const _Float16* __restrict__ Ckh,
             const _Float16* __restrict__ Ckl, const float* __restrict__ cbn,
             const float* __restrict__ cbk, float* __restrict__ q) {
    __shared__ _Float16 sAh[128 * 64], sAl[128 * 64];
    __shared__ _Float16 sBh[64 * 64],  sBl[64 * 64];
    __shared__ float bd_s[2][128];
    __shared__ int   bi_s[2][128];

    const int tid  = threadIdx.x;
    const int lane = tid & 63;
    const int wv   = tid >> 6;
    const int wr   = (wv >> 1) * 64;
    const int wch  = wv & 1;
    const int wc   = wch * 32;
    const int kr   = lane & 15;
    const int kg   = lane >> 4;
    const int r0   = blockIdx.x * 128;

    // stage A once: split h rows (f32 -> fp16 hi/lo)
    {
        const int m  = tid >> 1;
        const int q2 = (tid & 1) * 32;
        const float* src = h + (size_t)(r0 + m) * 64 + q2;
        float fv[32];
#pragma unroll
        for (int i = 0; i < 8; i++)
            *(float4*)&fv[i * 4] = *(const float4*)(src + i * 4);
#pragma unroll
        for (int c2 = 0; c2 < 4; c2++) {
            _Float16 hv[8], lv[8];
#pragma unroll
            for (int e = 0; e < 8; e++) {
                float xx = fv[c2 * 8 + e];
                _Float16 hb = (_Float16)xx;
                hv[e] = hb;
                lv[e] = (_Float16)((xx - (float)hb) * 4096.f);
            }
            int dst = m * 64 + (((q2 >> 3) + c2) ^ swz8(m)) * 8;
            *(uint4*)&sAh[dst] = *(uint4*)hv;
            *(uint4*)&sAl[dst] = *(uint4*)lv;
        }
    }

    float bestv[4][4];
    int   bestid[4][4];
#pragma unroll
    for (int rb = 0; rb < 4; rb++)
#pragma unroll
        for (int j = 0; j < 4; j++) { bestv[rb][j] = 3.4e38f; bestid[rb][j] = 0; }

    for (int ct = 0; ct < 8; ct++) {
        __syncthreads();
        // stage B tile: 64 codes x 64 k from pre-split codebook (swizzled copy)
        {
            const int c  = tid >> 2;
            const int kq = (tid & 3) * 16;
            const _Float16* s1 = Ckh + (size_t)(ct * 64 + c) * 64 + kq;
            const _Float16* s2 = Ckl + (size_t)(ct * 64 + c) * 64 + kq;
#pragma unroll
            for (int i = 0; i < 2; i++) {
                int dst = c * 64 + (((kq >> 3) + i) ^ swz8(c)) * 8;
                *(uint4*)&sBh[dst] = *(const uint4*)(s1 + i * 8);
                *(uint4*)&sBl[dst] = *(const uint4*)(s2 + i * 8);
            }
        }
        __syncthreads();

        f32x4 acc[4][2] = {};
        f32x4 acx[4][2] = {};
#pragma unroll
        for (int kh = 0; kh < 2; kh++) {
            const int cb = kh * 4 + kg;
            half8 ah[4], al[4], bh[2], bl[2];
#pragma unroll
            for (int rb = 0; rb < 4; rb++) {
                int m = wr + rb * 16 + kr;
                int off = m * 64 + (cb ^ swz8(m)) * 8;
                ah[rb] = *(const half8*)&sAh[off];
                al[rb] = *(const half8*)&sAl[off];
            }
#pragma unroll
            for (int nb = 0; nb < 2; nb++) {
                int n = wc + nb * 16 + kr;
                int off = n * 64 + (cb ^ swz8(n)) * 8;
                bh[nb] = *(const half8*)&sBh[off];
                bl[nb] = *(const half8*)&sBl[off];
            }
#pragma unroll
            for (int rb = 0; rb < 4; rb++)
#pragma unroll
                for (int nb = 0; nb < 2; nb++) {
                    acc[rb][nb] = __builtin_amdgcn_mfma_f32_16x16x32_f16(ah[rb], bh[nb], acc[rb][nb], 0, 0, 0);
                    acx[rb][nb] = __builtin_amdgcn_mfma_f32_16x16x32_f16(ah[rb], bl[nb], acx[rb][nb], 0, 0, 0);
                    acx[rb][nb] = __builtin_amdgcn_mfma_f32_16x16x32_f16(al[rb], bh[nb], acx[rb][nb], 0, 0, 0);
                }
        }
        // per-tile argmin update (codes ascending: nb asc, strict <)
#pragma unroll
        for (int nb = 0; nb < 2; nb++) {
            int code = ct * 64 + wc + nb * 16 + kr;
            float cn = cbn[code];
#pragma unroll
            for (int rb = 0; rb < 4; rb++)
#pragma unroll
                for (int j = 0; j < 4; j++) {
                    float dot = acc[rb][nb][j] + acx[rb][nb][j] * (1.0f / 4096.0f);
                    float dist = fmaf(-2.f, dot, cn);
                    if (dist < bestv[rb][j]) { bestv[rb][j] = dist; bestid[rb][j] = code; }
                }
        }
    }

    // reduce across the 16 same-row lanes (low 4 bits)
#pragma unroll
    for (int rb = 0; rb < 4; rb++)
#pragma unroll
        for (int j = 0; j < 4; j++) {
#pragma unroll
            for (int mask = 1; mask < 16; mask <<= 1) {
                float od = __shfl_xor(bestv[rb][j], mask, 64);
                int   oi = __shfl_xor(bestid[rb][j], mask, 64);
                if (od < bestv[rb][j] || (od == bestv[rb][j] && oi < bestid[rb][j])) {
                    bestv[rb][j] = od; bestid[rb][j] = oi;
                }
            }
            if (kr == 0) {
                int row = wr + rb * 16 + kg * 4 + j;
                bd_s[wch][row] = bestv[rb][j];
                bi_s[wch][row] = bestid[rb][j];
            }
        }
    __syncthreads();

    // merge code halves
    if (tid < 128) {
        float d0 = bd_s[0][tid], d1 = bd_s[1][tid];
        int   i0 = bi_s[0][tid], i1 = bi_s[1][tid];
        bi_s[0][tid] = (d1 < d0 || (d1 == d0 && i1 < i0)) ? i1 : i0;
    }
    __syncthreads();

    // gather selected codes
    {
        const int r = tid >> 1, hf = tid & 1;
        const int idx = bi_s[0][r];
        const float* src = cbk + (size_t)idx * 64 + hf * 32;
        float* dst = q + (size_t)(r0 + r) * 64 + hf * 32;
#pragma unroll
        for (int i = 0; i < 8; i++)
            *(float4*)(dst + i * 4) = *(const float4*)(src + i * 4);
    }
}

extern "C" void kernel_launch(void* const* d_in, const int* in_sizes, int n_in,
                              void* d_out, int out_size, void* d_ws, size_t ws_size,
                              hipStream_t stream) {
    const float* x   = (const float*)d_in[0];
    const float* w1  = (const float*)d_in[1];
    const float* b1  = (const float*)d_in[2];
    const float* w2  = (const float*)d_in[3];
    const float* b2  = (const float*)d_in[4];
    const float* w3  = (const float*)d_in[5];
    const float* b3  = (const float*)d_in[6];
    const float* cbk = (const float*)d_in[7];
    const float* w4  = (const float*)d_in[8];
    const float* b4  = (const float*)d_in[9];
    const float* w5  = (const float*)d_in[10];
    const float* b5  = (const float*)d_in[11];
    const float* w6  = (const float*)d_in[12];
    const float* b6  = (const float*)d_in[13];
    float* out = (float*)d_out;

    // ---- workspace overlay (~300 MiB) ----
    char* Wp = (char*)d_ws;
    _Float16* Xh = (_Float16*)Wp;                      // 32 MiB
    _Float16* Xl = Xh + (size_t)16777216;              // 32 MiB
    Wp += (size_t)67108864;
    float* h1 = (float*)Wp;                            // 128 MiB
    Wp += (size_t)134217728;
    float* h2 = (float*)Wp;                            // 64 MiB
    Wp += (size_t)67108864;
    float* h3 = (float*)Wp;                            // 16 MiB
    Wp += (size_t)16777216;
    float* q  = (float*)Wp;                            // 16 MiB
    Wp += (size_t)16777216;
    _Float16* Ckh = (_Float16*)Wp;                     // 64 KiB
    _Float16* Ckl = Ckh + (size_t)32768;               // 64 KiB
    float* cbn = (float*)(Ckl + (size_t)32768);        // 2 KiB
    float* y1 = h2;   // h2 dead after L3
    float* y2 = h1;   // h1 dead after L2

    dim3 blk(256);

    split_x<<<dim3(16384), blk, 0, stream>>>(x, Xh, Xl);
    cbk_prep<<<dim3(2), blk, 0, stream>>>(cbk, Ckh, Ckl, cbn);

    // encoder (L1: A padded to K=256, W has true KW=255 rows)
    sgemm<0, 128, true,  false><<<dim3(4, 2, FTS), blk, 0, stream>>>(Xh, Xl, nullptr, w1, b1, h1, BATCH, 256, IN_DIM, U0);
    sgemm<0, 128, false, false><<<dim3(2, 2, FTS), blk, 0, stream>>>(nullptr, nullptr, h1, w2, b2, h2, BATCH, U0, U0, U1);
    sgemm<0, 64,  false, false><<<dim3(1, 2, FTS), blk, 0, stream>>>(nullptr, nullptr, h2, w3, b3, h3, BATCH, U1, U1, DIM);
    // vector quantization (fp16-split MFMA)
    vq_mfma<<<dim3(512), blk, 0, stream>>>(h3, Ckh, Ckl, cbn, cbk, q);
    // decoder
    sgemm<0, 128, false, false><<<dim3(2, 2, FTS), blk, 0, stream>>>(nullptr, nullptr, q,  w4, b4, y1, BATCH, DIM, DIM, U1);
    sgemm<0, 128, false, false><<<dim3(4, 2, FTS), blk, 0, stream>>>(nullptr, nullptr, y1, w5, b5, y2, BATCH, U1, U1, U0);
    sgemm<1, 128, false, true ><<<dim3(2, 2, FTS), blk, 0, stream>>>(nullptr, nullptr, y2, w6, b6, out, BATCH, U0, U0, FTS);
}